// Round 9
// baseline (123.980 us; speedup 1.0000x reference)
//
#include <hip/hip_runtime.h>
#include <hip/hip_bf16.h>

#define BATCH 32768
#define NPAIR 64
#define NBLK  128
#define NTILE 1152

typedef __bf16 bf16x8 __attribute__((ext_vector_type(8)));
typedef float  f32x4  __attribute__((ext_vector_type(4)));
static_assert(sizeof(bf16x8) == 16, "bf16x8 must be 16B");

// ---- workspace byte offsets (absolute) ----
#define WS_CNT      0
#define WS_BASE     256
#define WS_BH       1024
#define WS_OFF      33792
#define WS_PAIR     66560
#define WS_ROWLIST  197632
#define WS_WT00     328704
#define WS_WT01     590848
#define WS_WT1P     1115136
#define WS_WT1A     1377280
#define WS_WT1O     2163712
#define WS_SCHED    2229248                    /* NTILE x int4 */
#define WS_F1       2248704                    /* [32800][256] bf16 (L00 out) */
#define WS_F2       (WS_F1 + 32800*256*2)      /* [32800][128] bf16 (L01 out) */
#define WS_F3       (WS_F2 + 32800*128*2)      /* [32800][256] bf16 (L1p out) */
#define WS_F4       WS_F1                      /* [32800][128] bf16 (L1a out), aliases dead F1 */

__device__ __forceinline__ unsigned short f2bf(float x) {
  __bf16 h = (__bf16)x;
  return __builtin_bit_cast(unsigned short, h);
}

__device__ __forceinline__ bf16x8 gather_frag(const float* __restrict__ inp,
                                              int rg, int colofs, int kc, int kcol) {
  bf16x8 a;
  if (rg >= 0) {
    const float* q = inp + (size_t)rg * 144 + colofs + kc * 32 + kcol;
    float4 u = *(const float4*)(q);
    float4 v = *(const float4*)(q + 4);
    a[0] = (__bf16)u.x; a[1] = (__bf16)u.y; a[2] = (__bf16)u.z; a[3] = (__bf16)u.w;
    a[4] = (__bf16)v.x; a[5] = (__bf16)v.y; a[6] = (__bf16)v.z; a[7] = (__bf16)v.w;
  } else {
    #pragma unroll
    for (int j = 0; j < 8; ++j) a[j] = (__bf16)0.f;
  }
  return a;
}

// Merged: blocks 0..239 transpose weights fp32->bf16 [m][o][i]; blocks 240..367 route.
__global__ __launch_bounds__(256) void k_combo(const float* __restrict__ w00,
                                               const float* __restrict__ w01,
                                               const float* __restrict__ w1p,
                                               const float* __restrict__ w1a,
                                               const float* __restrict__ w1o,
                                               const float* __restrict__ inp,
                                               char* __restrict__ ws) {
  __shared__ unsigned short lds[64 * 72];
  int bid = blockIdx.x;
  if (bid >= 240) {
    int* h = (int*)lds;
    int rbid = bid - 240;
    int t = threadIdx.x;
    if (t < NPAIR) h[t] = 0;
    __syncthreads();
    int r = rbid * 256 + t;
    const float* q = inp + (size_t)r * 144 + 128;
    float4 u0 = *(const float4*)(q + 0);
    float4 u1 = *(const float4*)(q + 4);
    float4 v0 = *(const float4*)(q + 8);
    float4 v1 = *(const float4*)(q + 12);
    int a0 = 0;
    if (u0.y > 0.5f) a0 = 1; if (u0.z > 0.5f) a0 = 2; if (u0.w > 0.5f) a0 = 3;
    if (u1.x > 0.5f) a0 = 4; if (u1.y > 0.5f) a0 = 5; if (u1.z > 0.5f) a0 = 6; if (u1.w > 0.5f) a0 = 7;
    int a1 = 0;
    if (v0.y > 0.5f) a1 = 1; if (v0.z > 0.5f) a1 = 2; if (v0.w > 0.5f) a1 = 3;
    if (v1.x > 0.5f) a1 = 4; if (v1.y > 0.5f) a1 = 5; if (v1.z > 0.5f) a1 = 6; if (v1.w > 0.5f) a1 = 7;
    int p = a0 * 8 + a1;
    ((int*)(ws + WS_PAIR))[r] = p;
    atomicAdd(&h[p], 1);
    __syncthreads();
    if (t < NPAIR) ((int*)(ws + WS_BH))[rbid * NPAIR + t] = h[t];
    return;
  }
  const float* src; unsigned short* dst; int I, O, lt;
  if (bid < 32)       { src = w00; dst = (unsigned short*)(ws + WS_WT00); I = 64;  O = 256; lt = bid; }
  else if (bid < 96)  { src = w01; dst = (unsigned short*)(ws + WS_WT01); I = 256; O = 128; lt = bid - 32; }
  else if (bid < 128) { src = w1p; dst = (unsigned short*)(ws + WS_WT1P); I = 64;  O = 256; lt = bid - 96; }
  else if (bid < 224) { src = w1a; dst = (unsigned short*)(ws + WS_WT1A); I = 384; O = 128; lt = bid - 128; }
  else                { src = w1o; dst = (unsigned short*)(ws + WS_WT1O); I = 128; O = 32;  lt = bid - 224; }
  int tI = I >> 6;
  int tO = (O + 63) >> 6;
  int m   = lt / (tI * tO);
  int rem = lt % (tI * tO);
  int ib = rem / tO, ob = rem % tO;
  int tx = threadIdx.x & 63, ty = threadIdx.x >> 6;
  const float* s = src + (size_t)m * I * O;
  #pragma unroll 4
  for (int s4 = 0; s4 < 16; ++s4) {
    int li = s4 * 4 + ty;
    int o  = ob * 64 + tx;
    float v = (o < O) ? s[(size_t)(ib * 64 + li) * O + o] : 0.f;
    lds[li * 72 + tx] = f2bf(v);
  }
  __syncthreads();
  unsigned short* d = dst + (size_t)m * O * I;
  #pragma unroll 4
  for (int s4 = 0; s4 < 16; ++s4) {
    int lo = s4 * 4 + ty;
    int o  = ob * 64 + lo;
    if (o < O) d[(size_t)o * I + ib * 64 + tx] = lds[tx * 72 + lo];
  }
}

// Scan: counts, bases, per-(block,pair) offsets, AND 32-row tile schedule.
__global__ __launch_bounds__(1024) void k_scan(const int* __restrict__ bh,
                                               int* __restrict__ cnt,
                                               int* __restrict__ base,
                                               int* __restrict__ off,
                                               int4* __restrict__ sched) {
  __shared__ int part[16][NPAIR];
  __shared__ int bs64[NPAIR];
  int tid = threadIdx.x;
  int p = tid & 63, c = tid >> 6;
  int loc[8]; int s = 0;
  #pragma unroll
  for (int i = 0; i < 8; ++i) { loc[i] = s; s += bh[(c * 8 + i) * NPAIR + p]; }
  part[c][p] = s;
  for (int j = tid; j < NTILE; j += 1024) sched[j] = make_int4(0, 0, 0, 0);
  __syncthreads();
  if (tid < 64) {
    int run = 0;
    #pragma unroll
    for (int c2 = 0; c2 < 16; ++c2) { int v = part[c2][p]; part[c2][p] = run; run += v; }
    cnt[p] = run;
    int x = run;
    #pragma unroll
    for (int d = 1; d < 64; d <<= 1) { int y = __shfl_up(x, d); if (p >= d) x += y; }
    int bs = x - run;
    base[p] = bs;
    bs64[p] = bs;
    int ntp = (run + 31) >> 5;
    int z = ntp;
    #pragma unroll
    for (int d = 1; d < 64; d <<= 1) { int y = __shfl_up(z, d); if (p >= d) z += y; }
    int tb = z - ntp;
    for (int t = 0; t < ntp; ++t)
      sched[tb + t] = make_int4(p, bs + t * 32, min(32, run - t * 32), 0);
  }
  __syncthreads();
  int add = part[c][p] + bs64[p];
  #pragma unroll
  for (int i = 0; i < 8; ++i) off[(c * 8 + i) * NPAIR + p] = loc[i] + add;
}

// Scatter: LDS-local rank + precomputed global offset. NO global atomics.
__global__ __launch_bounds__(256) void k_scatter(const int* __restrict__ pairArr,
                                                 const int* __restrict__ off,
                                                 int* __restrict__ rowlist) {
  __shared__ int h[NPAIR];
  int t = threadIdx.x;
  if (t < NPAIR) h[t] = 0;
  __syncthreads();
  int r = blockIdx.x * 256 + threadIdx.x;
  int p = pairArr[r];
  int rank = atomicAdd(&h[p], 1);
  rowlist[off[blockIdx.x * NPAIR + p] + rank] = r;
}

// ===================== barrier-free grouped GEMM layers =====================
// One wave = one 16-row x 64-col output unit. No LDS, no __syncthreads.
// Activations row-major in ws, indexed by rowlist POSITION (p-grouped order).

// gemmA: L00 (inp[:, :64] @ wt00[e0] -> F1) and L1p (inp[:,64:128] @ wt1p[e1] -> F3).
// grid = NTILE*4; unit u = (bid&3)*4+w in 0..15: L=u>>3, sub=(u&7)>>2, nch=u&3.
__global__ __launch_bounds__(256, 4) void k_gemmA(const float* __restrict__ inp,
                                                  const float* __restrict__ b00,
                                                  const float* __restrict__ b1p,
                                                  char* __restrict__ ws) {
  int w = threadIdx.x >> 6, lane = threadIdx.x & 63;
  int ln = lane & 15, lq = lane >> 4, kcol = lq * 8;
  int tile = blockIdx.x >> 2;
  int u = ((blockIdx.x & 3) << 2) | w;
  int L = u >> 3, rem = u & 7, sub = rem >> 2, nch = rem & 3;
  int4 se = ((const int4*)(ws + WS_SCHED))[tile];
  int nr = se.z;
  if (nr <= 0) return;
  int p = se.x, rb = se.y;
  int e = L ? (p & 7) : (p >> 3);
  const int* rl = (const int*)(ws + WS_ROWLIST) + rb;
  const unsigned short* wt = (const unsigned short*)(ws + (L ? WS_WT1P : WS_WT00));
  const float* bias = L ? b1p : b00;
  unsigned short* F = (unsigned short*)(ws + (L ? WS_F3 : WS_F1));
  int colofs = L ? 64 : 0;

  int rloc = sub * 16 + ln;
  int rg = (rloc < nr) ? rl[rloc] : -1;

  const f32x4 z4 = {0.f, 0.f, 0.f, 0.f};
  f32x4 acc[4] = {z4, z4, z4, z4};
  #pragma unroll
  for (int kc = 0; kc < 2; ++kc) {
    bf16x8 a = gather_frag(inp, rg, colofs, kc, kcol);
    #pragma unroll
    for (int nt = 0; nt < 4; ++nt) {
      int n = nch * 64 + nt * 16 + ln;
      bf16x8 b = *(const bf16x8*)(wt + ((size_t)(e * 256 + n) * 64 + kc * 32 + kcol));
      acc[nt] = __builtin_amdgcn_mfma_f32_16x16x32_bf16(a, b, acc[nt], 0, 0, 0);
    }
  }
  #pragma unroll
  for (int nt = 0; nt < 4; ++nt) {
    int n = nch * 64 + nt * 16 + ln;
    float bs = bias[e * 256 + n];
    #pragma unroll
    for (int r = 0; r < 4; ++r) {
      int row_l = sub * 16 + lq * 4 + r;
      if (row_l < nr) {
        float v = fmaxf(acc[nt][r] + bs, 0.f);
        F[(size_t)(rb + row_l) * 256 + n] = f2bf(v);
      }
    }
  }
}

// gemmB: L01 (F1 @ wt01[e0] -> F2). grid = NTILE; unit = wave: sub=w>>1, nch=w&1.
__global__ __launch_bounds__(256, 4) void k_gemmB(const float* __restrict__ b01,
                                                  char* __restrict__ ws) {
  int w = threadIdx.x >> 6, lane = threadIdx.x & 63;
  int ln = lane & 15, lq = lane >> 4, kcol = lq * 8;
  int tile = blockIdx.x;
  int sub = w >> 1, nch = w & 1;
  int4 se = ((const int4*)(ws + WS_SCHED))[tile];
  int nr = se.z;
  if (nr <= 0) return;
  int p = se.x, rb = se.y;
  int e0 = p >> 3;
  const unsigned short* F1 = (const unsigned short*)(ws + WS_F1);
  const unsigned short* wt = (const unsigned short*)(ws + WS_WT01);
  unsigned short* F2 = (unsigned short*)(ws + WS_F2);

  const f32x4 z4 = {0.f, 0.f, 0.f, 0.f};
  f32x4 acc[4] = {z4, z4, z4, z4};
  #pragma unroll
  for (int kc = 0; kc < 8; ++kc) {
    bf16x8 a = *(const bf16x8*)(F1 + (size_t)(rb + sub * 16 + ln) * 256 + kc * 32 + kcol);
    #pragma unroll
    for (int nt = 0; nt < 4; ++nt) {
      int n = nch * 64 + nt * 16 + ln;
      bf16x8 b = *(const bf16x8*)(wt + ((size_t)(e0 * 128 + n) * 256 + kc * 32 + kcol));
      acc[nt] = __builtin_amdgcn_mfma_f32_16x16x32_bf16(a, b, acc[nt], 0, 0, 0);
    }
  }
  #pragma unroll
  for (int nt = 0; nt < 4; ++nt) {
    int n = nch * 64 + nt * 16 + ln;
    float bs = b01[e0 * 128 + n];
    #pragma unroll
    for (int r = 0; r < 4; ++r) {
      int row_l = sub * 16 + lq * 4 + r;
      if (row_l < nr) {
        float v = fmaxf(acc[nt][r] + bs, 0.f);
        F2[(size_t)(rb + row_l) * 128 + n] = f2bf(v);
      }
    }
  }
}

// gemmC: L1a ([F2 | F3] @ wt1a[e1] -> F4). grid = NTILE; K=384.
__global__ __launch_bounds__(256, 4) void k_gemmC(const float* __restrict__ b1a,
                                                  char* __restrict__ ws) {
  int w = threadIdx.x >> 6, lane = threadIdx.x & 63;
  int ln = lane & 15, lq = lane >> 4, kcol = lq * 8;
  int tile = blockIdx.x;
  int sub = w >> 1, nch = w & 1;
  int4 se = ((const int4*)(ws + WS_SCHED))[tile];
  int nr = se.z;
  if (nr <= 0) return;
  int p = se.x, rb = se.y;
  int e1 = p & 7;
  const unsigned short* F2 = (const unsigned short*)(ws + WS_F2);
  const unsigned short* F3 = (const unsigned short*)(ws + WS_F3);
  const unsigned short* wt = (const unsigned short*)(ws + WS_WT1A);
  unsigned short* F4 = (unsigned short*)(ws + WS_F4);

  int row = rb + sub * 16 + ln;
  const f32x4 z4 = {0.f, 0.f, 0.f, 0.f};
  f32x4 acc[4] = {z4, z4, z4, z4};
  #pragma unroll
  for (int kc = 0; kc < 12; ++kc) {
    bf16x8 a;
    if (kc < 4) a = *(const bf16x8*)(F2 + (size_t)row * 128 + kc * 32 + kcol);
    else        a = *(const bf16x8*)(F3 + (size_t)row * 256 + (kc - 4) * 32 + kcol);
    #pragma unroll
    for (int nt = 0; nt < 4; ++nt) {
      int n = nch * 64 + nt * 16 + ln;
      bf16x8 b = *(const bf16x8*)(wt + ((size_t)(e1 * 128 + n) * 384 + kc * 32 + kcol));
      acc[nt] = __builtin_amdgcn_mfma_f32_16x16x32_bf16(a, b, acc[nt], 0, 0, 0);
    }
  }
  #pragma unroll
  for (int nt = 0; nt < 4; ++nt) {
    int n = nch * 64 + nt * 16 + ln;
    float bs = b1a[e1 * 128 + n];
    #pragma unroll
    for (int r = 0; r < 4; ++r) {
      int row_l = sub * 16 + lq * 4 + r;
      if (row_l < nr) {
        float v = fmaxf(acc[nt][r] + bs, 0.f);
        F4[(size_t)(rb + row_l) * 128 + n] = f2bf(v);
      }
    }
  }
}

// gemmD: L1o (F4 @ wt1o[e1] -> out, fp32 scatter). grid = NTILE/2; 2 units/tile.
__global__ __launch_bounds__(256, 4) void k_gemmD(const float* __restrict__ b1o,
                                                  char* __restrict__ ws,
                                                  float* __restrict__ out) {
  int w = threadIdx.x >> 6, lane = threadIdx.x & 63;
  int ln = lane & 15, lq = lane >> 4, kcol = lq * 8;
  int unit = blockIdx.x * 4 + w;
  int tile = unit >> 1, sub = unit & 1;
  int4 se = ((const int4*)(ws + WS_SCHED))[tile];
  int nr = se.z;
  if (nr <= 0) return;
  int p = se.x, rb = se.y;
  int e1 = p & 7;
  const int* rl = (const int*)(ws + WS_ROWLIST) + rb;
  const unsigned short* F4 = (const unsigned short*)(ws + WS_F4);
  const unsigned short* wt = (const unsigned short*)(ws + WS_WT1O);

  const f32x4 z4 = {0.f, 0.f, 0.f, 0.f};
  f32x4 acc[2] = {z4, z4};
  #pragma unroll
  for (int kc = 0; kc < 4; ++kc) {
    bf16x8 a = *(const bf16x8*)(F4 + (size_t)(rb + sub * 16 + ln) * 128 + kc * 32 + kcol);
    #pragma unroll
    for (int nt = 0; nt < 2; ++nt) {
      int n = nt * 16 + ln;
      bf16x8 b = *(const bf16x8*)(wt + ((size_t)(e1 * 32 + n) * 128 + kc * 32 + kcol));
      acc[nt] = __builtin_amdgcn_mfma_f32_16x16x32_bf16(a, b, acc[nt], 0, 0, 0);
    }
  }
  #pragma unroll
  for (int nt = 0; nt < 2; ++nt) {
    int n = nt * 16 + ln;
    float bs = b1o[e1 * 32 + n];
    #pragma unroll
    for (int r = 0; r < 4; ++r) {
      int row_l = sub * 16 + lq * 4 + r;
      if (row_l < nr) {
        int rg = rl[row_l];
        out[(size_t)rg * 32 + n] = acc[nt][r] + bs;
      }
    }
  }
}

extern "C" void kernel_launch(void* const* d_in, const int* in_sizes, int n_in,
                              void* d_out, int out_size, void* d_ws, size_t ws_size,
                              hipStream_t stream) {
  const float* inp = (const float*)d_in[0];
  const float* w00 = (const float*)d_in[1];
  const float* b00 = (const float*)d_in[2];
  const float* w01 = (const float*)d_in[3];
  const float* b01 = (const float*)d_in[4];
  const float* w1p = (const float*)d_in[5];
  const float* b1p = (const float*)d_in[6];
  const float* w1a = (const float*)d_in[7];
  const float* b1a = (const float*)d_in[8];
  const float* w1o = (const float*)d_in[9];
  const float* b1o = (const float*)d_in[10];
  char*  ws  = (char*)d_ws;
  float* out = (float*)d_out;

  k_combo<<<368, 256, 0, stream>>>(w00, w01, w1p, w1a, w1o, inp, ws);
  k_scan<<<1, 1024, 0, stream>>>((const int*)(ws + WS_BH), (int*)(ws + WS_CNT),
                                 (int*)(ws + WS_BASE), (int*)(ws + WS_OFF),
                                 (int4*)(ws + WS_SCHED));
  k_scatter<<<NBLK, 256, 0, stream>>>((const int*)(ws + WS_PAIR),
                                      (const int*)(ws + WS_OFF),
                                      (int*)(ws + WS_ROWLIST));
  k_gemmA<<<NTILE * 4, 256, 0, stream>>>(inp, b00, b1p, ws);
  k_gemmB<<<NTILE, 256, 0, stream>>>(b01, ws);
  k_gemmC<<<NTILE, 256, 0, stream>>>(b1a, ws);
  k_gemmD<<<NTILE / 2, 256, 0, stream>>>(b1o, ws, out);
}

// Round 10
// 61.092 us; speedup vs baseline: 2.0294x; 2.0294x over previous
//
#include <hip/hip_runtime.h>
#include <hip/hip_bf16.h>

#define BATCH 32768
#define NPAIR 64
#define NBLK  128

typedef __bf16 bf16x8 __attribute__((ext_vector_type(8)));
typedef float  f32x4  __attribute__((ext_vector_type(4)));
static_assert(sizeof(bf16x8) == 16, "bf16x8 must be 16B");

// ---- workspace byte offsets ----
#define WS_CNT      0
#define WS_BASE     256        /* padded (32-aligned) pair bases */
#define WS_BH       1024
#define WS_OFF      33792
#define WS_PAIR     66560
#define WS_ROWLIST  197632     /* padded, 34816 ints */
#define WS_WF00     336896     /* frag-major [m][NT16][KC2][64]x16B = 32KB/m */
#define WS_WF01     599040     /* [m][NT8][KC8][64] = 64KB/m */
#define WS_WF1P     1123328    /* 32KB/m */
#define WS_WF1A     1385472    /* [m][NT8][KC12][64] = 96KB/m */
#define WS_WF1O     2171904    /* [m][NT2][KC4][64] = 8KB/m */
#define WS_F2       2237440    /* [pos16<=2176][nb8][16][16] bf16 = 8.9MB */

__device__ __forceinline__ unsigned short f2bf(float x) {
  __bf16 h = (__bf16)x;
  return __builtin_bit_cast(unsigned short, h);
}

// one-asm batch pin (forces the 8 prefetched F2 fragments to materialize here)
#define PIN8(A) asm volatile("" :: \
  "v"((A)[0]),"v"((A)[1]),"v"((A)[2]),"v"((A)[3]), \
  "v"((A)[4]),"v"((A)[5]),"v"((A)[6]),"v"((A)[7]))

__device__ __forceinline__ bf16x8 gather_frag(const float* __restrict__ inp,
                                              int rg, int colofs, int kc, int kcol) {
  bf16x8 a;
  if (rg >= 0) {
    const float* q = inp + (size_t)rg * 144 + colofs + kc * 32 + kcol;
    float4 u = *(const float4*)(q);
    float4 v = *(const float4*)(q + 4);
    a[0] = (__bf16)u.x; a[1] = (__bf16)u.y; a[2] = (__bf16)u.z; a[3] = (__bf16)u.w;
    a[4] = (__bf16)v.x; a[5] = (__bf16)v.y; a[6] = (__bf16)v.z; a[7] = (__bf16)v.w;
  } else {
    #pragma unroll
    for (int j = 0; j < 8; ++j) a[j] = (__bf16)0.f;
  }
  return a;
}

// Blocks 0..239: weight fp32 -> bf16 MFMA-fragment-major. Blocks 240..367: route.
__global__ __launch_bounds__(256) void k_combo(const float* __restrict__ w00,
                                               const float* __restrict__ w01,
                                               const float* __restrict__ w1p,
                                               const float* __restrict__ w1a,
                                               const float* __restrict__ w1o,
                                               const float* __restrict__ inp,
                                               char* __restrict__ ws) {
  __shared__ unsigned short lds[64 * 72];
  int bid = blockIdx.x;
  if (bid >= 240) {
    int* h = (int*)lds;
    int rbid = bid - 240;
    int t = threadIdx.x;
    if (t < NPAIR) h[t] = 0;
    __syncthreads();
    int r = rbid * 256 + t;
    const float* q = inp + (size_t)r * 144 + 128;
    float4 u0 = *(const float4*)(q + 0);
    float4 u1 = *(const float4*)(q + 4);
    float4 v0 = *(const float4*)(q + 8);
    float4 v1 = *(const float4*)(q + 12);
    int a0 = 0;
    if (u0.y > 0.5f) a0 = 1; if (u0.z > 0.5f) a0 = 2; if (u0.w > 0.5f) a0 = 3;
    if (u1.x > 0.5f) a0 = 4; if (u1.y > 0.5f) a0 = 5; if (u1.z > 0.5f) a0 = 6; if (u1.w > 0.5f) a0 = 7;
    int a1 = 0;
    if (v0.y > 0.5f) a1 = 1; if (v0.z > 0.5f) a1 = 2; if (v0.w > 0.5f) a1 = 3;
    if (v1.x > 0.5f) a1 = 4; if (v1.y > 0.5f) a1 = 5; if (v1.z > 0.5f) a1 = 6; if (v1.w > 0.5f) a1 = 7;
    int p = a0 * 8 + a1;
    ((int*)(ws + WS_PAIR))[r] = p;
    atomicAdd(&h[p], 1);
    __syncthreads();
    if (t < NPAIR) ((int*)(ws + WS_BH))[rbid * NPAIR + t] = h[t];
    return;
  }
  const float* src; char* dst; int I, O, lt, NT, KC;
  if (bid < 32)       { src = w00; dst = ws + WS_WF00; I = 64;  O = 256; lt = bid;       NT = 16; KC = 2; }
  else if (bid < 96)  { src = w01; dst = ws + WS_WF01; I = 256; O = 128; lt = bid - 32;  NT = 8;  KC = 8; }
  else if (bid < 128) { src = w1p; dst = ws + WS_WF1P; I = 64;  O = 256; lt = bid - 96;  NT = 16; KC = 2; }
  else if (bid < 224) { src = w1a; dst = ws + WS_WF1A; I = 384; O = 128; lt = bid - 128; NT = 8;  KC = 12; }
  else                { src = w1o; dst = ws + WS_WF1O; I = 128; O = 32;  lt = bid - 224; NT = 2;  KC = 4; }
  int tI = I >> 6;
  int tO = (O + 63) >> 6;
  int m   = lt / (tI * tO);
  int rem = lt % (tI * tO);
  int ib = rem / tO, ob = rem % tO;
  int tx = threadIdx.x & 63, ty = threadIdx.x >> 6;
  const float* s = src + (size_t)m * I * O;
  // load 64(i) x 64(o) tile, cvt to bf16: lds[i_local*72 + o_local]
  #pragma unroll 4
  for (int s4 = 0; s4 < 16; ++s4) {
    int li = s4 * 4 + ty;
    int o  = ob * 64 + tx;
    float v = (o < O) ? s[(size_t)(ib * 64 + li) * O + o] : 0.f;
    lds[li * 72 + tx] = f2bf(v);
  }
  __syncthreads();
  // emit 8 fragments (ntl 0..3 x kcl 0..1): frag element j of lane (ln,lq) =
  // W[i = kcg*32 + lq*8 + j][o = ntg*16 + ln]
  int lane = threadIdx.x & 63, u = threadIdx.x >> 6;
  int ln = lane & 15, lq = lane >> 4;
  #pragma unroll
  for (int it = 0; it < 2; ++it) {
    int fi  = it * 4 + u;
    int ntl = fi >> 1, kcl = fi & 1;
    int ntg = ob * 4 + ntl, kcg = ib * 2 + kcl;
    if (ntg * 16 < O) {
      bf16x8 f;
      #pragma unroll
      for (int j = 0; j < 8; ++j)
        f[j] = __builtin_bit_cast(__bf16, lds[(kcl * 32 + lq * 8 + j) * 72 + ntl * 16 + ln]);
      *(bf16x8*)(dst + (((size_t)(m * NT + ntg) * KC + kcg) * 64 + lane) * 16) = f;
    }
  }
}

// Scan: counts, PADDED (32-aligned) bases, per-(block,pair) scatter offsets.
__global__ __launch_bounds__(1024) void k_scan(const int* __restrict__ bh,
                                               int* __restrict__ cnt,
                                               int* __restrict__ base,
                                               int* __restrict__ off) {
  __shared__ int part[16][NPAIR];
  __shared__ int pb64[NPAIR];
  int tid = threadIdx.x;
  int p = tid & 63, c = tid >> 6;
  int loc[8]; int s = 0;
  #pragma unroll
  for (int i = 0; i < 8; ++i) { loc[i] = s; s += bh[(c * 8 + i) * NPAIR + p]; }
  part[c][p] = s;
  __syncthreads();
  if (tid < 64) {
    int run = 0;
    #pragma unroll
    for (int c2 = 0; c2 < 16; ++c2) { int v = part[c2][p]; part[c2][p] = run; run += v; }
    cnt[p] = run;
    int ntp = (run + 31) >> 5;
    int z = ntp;
    #pragma unroll
    for (int d = 1; d < 64; d <<= 1) { int y = __shfl_up(z, d); if (p >= d) z += y; }
    int pbase = (z - ntp) * 32;
    base[p] = pbase;
    pb64[p] = pbase;
  }
  __syncthreads();
  int add = part[c][p] + pb64[p];
  #pragma unroll
  for (int i = 0; i < 8; ++i) off[(c * 8 + i) * NPAIR + p] = loc[i] + add;
}

__global__ __launch_bounds__(256) void k_scatter(const int* __restrict__ pairArr,
                                                 const int* __restrict__ off,
                                                 int* __restrict__ rowlist) {
  __shared__ int h[NPAIR];
  int t = threadIdx.x;
  if (t < NPAIR) h[t] = 0;
  __syncthreads();
  int r = blockIdx.x * 256 + threadIdx.x;
  int p = pairArr[r];
  int rank = atomicAdd(&h[p], 1);
  rowlist[off[blockIdx.x * NPAIR + p] + rank] = r;
}

// Kernel A: e0-branch. Per-pair persistent block (p = bid>>2, slice = bid&3).
// LDS: WF00 32KB @0, WF01 64KB @32K, H1 16KB @96K. All B-frags from LDS
// (lane-contiguous ds_read_b128); F2 written to global in 16x16-block layout.
__global__ __launch_bounds__(512, 1) void k_fwdA(
    const float* __restrict__ inp,
    const float* __restrict__ b00, const float* __restrict__ b01,
    char* __restrict__ ws)
{
  __shared__ char smem[114688];
  unsigned short* H1m = (unsigned short*)(smem + 98304);

  int p     = blockIdx.x >> 2;
  int slice = blockIdx.x & 3;
  int e0 = p >> 3;
  int cnt = ((const int*)(ws + WS_CNT))[p];
  int pbase = ((const int*)(ws + WS_BASE))[p];
  int ntp = (cnt + 31) >> 5;
  if (slice >= ntp) return;
  const int* rlbase = (const int*)(ws + WS_ROWLIST) + pbase;
  char* f2 = ws + WS_F2;

  int tid = threadIdx.x;
  // stage WF00[e0] (32KB) + WF01[e0] (64KB) -> LDS, contiguous copies
  {
    const float4* s0 = (const float4*)(ws + WS_WF00 + (size_t)e0 * 32768);
    float4* d0 = (float4*)smem;
    #pragma unroll
    for (int i = 0; i < 4; ++i) d0[tid + i * 512] = s0[tid + i * 512];
    const float4* s1 = (const float4*)(ws + WS_WF01 + (size_t)e0 * 65536);
    float4* d1 = (float4*)(smem + 32768);
    #pragma unroll
    for (int i = 0; i < 8; ++i) d1[tid + i * 512] = s1[tid + i * 512];
  }

  int lane = tid & 63;
  int w    = tid >> 6;
  int ln = lane & 15, lq = lane >> 4, kcol = lq * 8;

  float bias00[2];
  #pragma unroll
  for (int nt = 0; nt < 2; ++nt) bias00[nt] = b00[e0 * 256 + w * 32 + nt * 16 + ln];
  float bias01 = b01[e0 * 128 + w * 16 + ln];

  const f32x4 z4 = {0.f, 0.f, 0.f, 0.f};
  __syncthreads();  // weights staged

  for (int t = slice; t < ntp; t += 4) {
    int nr = min(32, cnt - t * 32);
    int rb = pbase + t * 32;
    const int* rl = rlbase + t * 32;

    int rowA[2];
    #pragma unroll
    for (int mt = 0; mt < 2; ++mt) {
      int rloc = mt * 16 + ln;
      rowA[mt] = (rloc < nr) ? rl[rloc] : -1;
    }
    bf16x8 axf[2][2];
    #pragma unroll
    for (int mt = 0; mt < 2; ++mt)
      #pragma unroll
      for (int kc = 0; kc < 2; ++kc)
        axf[mt][kc] = gather_frag(inp, rowA[mt], 0, kc, kcol);

    // P1: L00 -> H1 (wave w covers cols w*32..w*32+31)
    #pragma unroll
    for (int nt = 0; nt < 2; ++nt) {
      int n = w * 32 + nt * 16 + ln;
      int ntg = w * 2 + nt;
      f32x4 acc[2] = {z4, z4};
      #pragma unroll
      for (int kc = 0; kc < 2; ++kc) {
        bf16x8 bfr = *(const bf16x8*)(smem + ((ntg * 2 + kc) * 64 + lane) * 16);
        #pragma unroll
        for (int mt = 0; mt < 2; ++mt)
          acc[mt] = __builtin_amdgcn_mfma_f32_16x16x32_bf16(axf[mt][kc], bfr, acc[mt], 0, 0, 0);
      }
      #pragma unroll
      for (int mt = 0; mt < 2; ++mt)
        #pragma unroll
        for (int r = 0; r < 4; ++r) {
          int row = mt * 16 + lq * 4 + r;
          float v = fmaxf(acc[mt][r] + bias00[nt], 0.f);
          H1m[(row * 512 + ((n << 1) ^ ((row & 7) << 4))) >> 1] = f2bf(v);
        }
    }
    __syncthreads();

    // P2: L01 (wave w covers cols w*16..w*16+15) -> F2 global, block layout
    {
      f32x4 acc[2] = {z4, z4};
      #pragma unroll
      for (int kc = 0; kc < 8; ++kc) {
        bf16x8 bfr = *(const bf16x8*)(smem + 32768 + ((w * 8 + kc) * 64 + lane) * 16);
        #pragma unroll
        for (int mt = 0; mt < 2; ++mt) {
          int row = mt * 16 + ln;
          bf16x8 afr = *(const bf16x8*)&H1m[(row * 512 + (((kc * 32 + kcol) << 1) ^ ((row & 7) << 4))) >> 1];
          acc[mt] = __builtin_amdgcn_mfma_f32_16x16x32_bf16(afr, bfr, acc[mt], 0, 0, 0);
        }
      }
      // F2[pos16][nb=w][rowin][colin]
      #pragma unroll
      for (int mt = 0; mt < 2; ++mt) {
        int pos16 = (rb >> 4) + mt;
        char* bb = f2 + ((size_t)(pos16 * 8 + w) * 512);
        #pragma unroll
        for (int r = 0; r < 4; ++r) {
          float v = fmaxf(acc[mt][r] + bias01, 0.f);
          *(unsigned short*)(bb + (lq * 4 + r) * 32 + ln * 2) = f2bf(v);
        }
      }
    }
    __syncthreads();
  }
}

// Kernel B: e1-branch. LDS: WF1P 32KB @0, WF1A 96KB @32K, WF1O 8KB @128K,
// G 16KB @136K (G2 8KB aliases G). F2 A-frags prefetched (contiguous 16B/lane).
__global__ __launch_bounds__(512, 1) void k_fwdB(
    const float* __restrict__ inp,
    const float* __restrict__ b1p, const float* __restrict__ b1a,
    const float* __restrict__ b1o,
    char* __restrict__ ws, float* __restrict__ out)
{
  __shared__ char smem[155648];
  unsigned short* G  = (unsigned short*)(smem + 139264);
  unsigned short* G2 = (unsigned short*)(smem + 139264);  // aliases G (guarded by bars)

  int p     = blockIdx.x >> 2;
  int slice = blockIdx.x & 3;
  int e1 = p & 7;
  int cnt = ((const int*)(ws + WS_CNT))[p];
  int pbase = ((const int*)(ws + WS_BASE))[p];
  int ntp = (cnt + 31) >> 5;
  if (slice >= ntp) return;
  const int* rlbase = (const int*)(ws + WS_ROWLIST) + pbase;
  const char* f2 = ws + WS_F2;

  int tid = threadIdx.x;
  // stage WF1P(32K) + WF1A(96K) + WF1O(8K)
  {
    const float4* s0 = (const float4*)(ws + WS_WF1P + (size_t)e1 * 32768);
    float4* d0 = (float4*)smem;
    #pragma unroll
    for (int i = 0; i < 4; ++i) d0[tid + i * 512] = s0[tid + i * 512];
    const float4* s1 = (const float4*)(ws + WS_WF1A + (size_t)e1 * 98304);
    float4* d1 = (float4*)(smem + 32768);
    #pragma unroll
    for (int i = 0; i < 12; ++i) d1[tid + i * 512] = s1[tid + i * 512];
    if (tid < 512) {
      const float4* s2 = (const float4*)(ws + WS_WF1O + (size_t)e1 * 8192);
      float4* d2 = (float4*)(smem + 131072);
      if (tid < 512) d2[tid] = s2[tid];
    }
  }

  int lane = tid & 63;
  int w    = tid >> 6;
  int ln = lane & 15, lq = lane >> 4, kcol = lq * 8;

  float bias1p[2];
  #pragma unroll
  for (int nt = 0; nt < 2; ++nt) bias1p[nt] = b1p[e1 * 256 + w * 32 + nt * 16 + ln];
  float bias1a = b1a[e1 * 128 + w * 16 + ln];
  float bias1o = (w < 4) ? b1o[e1 * 32 + (w >> 1) * 16 + ln] : 0.f;

  const f32x4 z4 = {0.f, 0.f, 0.f, 0.f};
  __syncthreads();  // weights staged

  for (int t = slice; t < ntp; t += 4) {
    int nr = min(32, cnt - t * 32);
    int rb = pbase + t * 32;
    const int* rl = rlbase + t * 32;

    int rowA[2];
    #pragma unroll
    for (int mt = 0; mt < 2; ++mt) {
      int rloc = mt * 16 + ln;
      rowA[mt] = (rloc < nr) ? rl[rloc] : -1;
    }
    bf16x8 axf[2][2];
    #pragma unroll
    for (int mt = 0; mt < 2; ++mt)
      #pragma unroll
      for (int kc = 0; kc < 2; ++kc)
        axf[mt][kc] = gather_frag(inp, rowA[mt], 64, kc, kcol);

    // prefetch F2 A-frags (contiguous 16B/lane): ff[mt][kcb], k = kcb*32+lq*8+j
    bf16x8 ff[8];
    #pragma unroll
    for (int mt = 0; mt < 2; ++mt) {
      int pos16 = (rb >> 4) + mt;
      #pragma unroll
      for (int kcb = 0; kcb < 4; ++kcb) {
        const char* bb = f2 + ((size_t)(pos16 * 8 + kcb * 2 + (lq >> 1)) * 512);
        ff[mt * 4 + kcb] = *(const bf16x8*)(bb + ln * 32 + (lq & 1) * 16);
      }
    }
    PIN8(ff);

    // P1: L1p -> G (swizzled)
    #pragma unroll
    for (int nt = 0; nt < 2; ++nt) {
      int n = w * 32 + nt * 16 + ln;
      int ntg = w * 2 + nt;
      f32x4 acc[2] = {z4, z4};
      #pragma unroll
      for (int kc = 0; kc < 2; ++kc) {
        bf16x8 bfr = *(const bf16x8*)(smem + ((ntg * 2 + kc) * 64 + lane) * 16);
        #pragma unroll
        for (int mt = 0; mt < 2; ++mt)
          acc[mt] = __builtin_amdgcn_mfma_f32_16x16x32_bf16(axf[mt][kc], bfr, acc[mt], 0, 0, 0);
      }
      #pragma unroll
      for (int mt = 0; mt < 2; ++mt)
        #pragma unroll
        for (int r = 0; r < 4; ++r) {
          int row = mt * 16 + lq * 4 + r;
          float v = fmaxf(acc[mt][r] + bias1p[nt], 0.f);
          G[(row * 512 + ((n << 1) ^ ((row & 7) << 4))) >> 1] = f2bf(v);
        }
    }
    __syncthreads();  // G ready

    // P2: L1a = [F2-frags (k<128) | G (k>=128)] @ WF1A -> acc (regs)
    f32x4 acc1a[2] = {z4, z4};
    #pragma unroll
    for (int kc = 0; kc < 12; ++kc) {
      bf16x8 bfr = *(const bf16x8*)(smem + 32768 + ((w * 12 + kc) * 64 + lane) * 16);
      #pragma unroll
      for (int mt = 0; mt < 2; ++mt) {
        bf16x8 afr;
        if (kc < 4) {
          afr = ff[mt * 4 + kc];
        } else {
          int kk = kc - 4;
          int row = mt * 16 + ln;
          afr = *(const bf16x8*)&G[(row * 512 + (((kk * 32 + kcol) << 1) ^ ((row & 7) << 4))) >> 1];
        }
        acc1a[mt] = __builtin_amdgcn_mfma_f32_16x16x32_bf16(afr, bfr, acc1a[mt], 0, 0, 0);
      }
    }
    __syncthreads();  // G reads done; safe to overwrite via G2 alias

    // write G2 = relu(acc1a + b1a)  (32x128, swizzled, aliases G)
    {
      int n = w * 16 + ln;
      #pragma unroll
      for (int mt = 0; mt < 2; ++mt)
        #pragma unroll
        for (int r = 0; r < 4; ++r) {
          int row = mt * 16 + lq * 4 + r;
          float v = fmaxf(acc1a[mt][r] + bias1a, 0.f);
          G2[(row * 256 + ((n << 1) ^ ((row & 7) << 4))) >> 1] = f2bf(v);
        }
    }
    __syncthreads();  // G2 ready

    // P3: L1o (waves 0..3): G2 @ WF1O -> out, fp32 scatter
    if (w < 4) {
      int mt = w & 1;
      int n  = (w >> 1) * 16 + ln;
      f32x4 acc = z4;
      #pragma unroll
      for (int kc = 0; kc < 4; ++kc) {
        int row = mt * 16 + ln;
        bf16x8 afr = *(const bf16x8*)&G2[(row * 256 + (((kc * 32 + kcol) << 1) ^ ((row & 7) << 4))) >> 1];
        bf16x8 bfr = *(const bf16x8*)(smem + 131072 + (((w >> 1) * 4 + kc) * 64 + lane) * 16);
        acc = __builtin_amdgcn_mfma_f32_16x16x32_bf16(afr, bfr, acc, 0, 0, 0);
      }
      #pragma unroll
      for (int r = 0; r < 4; ++r) {
        int row = mt * 16 + lq * 4 + r;
        if (row < nr) {
          int rg = rl[row];
          out[(size_t)rg * 32 + n] = acc[r] + bias1o;
        }
      }
    }
    __syncthreads();  // G2 reads done before next tile rewrites G
  }
}

extern "C" void kernel_launch(void* const* d_in, const int* in_sizes, int n_in,
                              void* d_out, int out_size, void* d_ws, size_t ws_size,
                              hipStream_t stream) {
  const float* inp = (const float*)d_in[0];
  const float* w00 = (const float*)d_in[1];
  const float* b00 = (const float*)d_in[2];
  const float* w01 = (const float*)d_in[3];
  const float* b01 = (const float*)d_in[4];
  const float* w1p = (const float*)d_in[5];
  const float* b1p = (const float*)d_in[6];
  const float* w1a = (const float*)d_in[7];
  const float* b1a = (const float*)d_in[8];
  const float* w1o = (const float*)d_in[9];
  const float* b1o = (const float*)d_in[10];
  char*  ws  = (char*)d_ws;
  float* out = (float*)d_out;

  k_combo<<<368, 256, 0, stream>>>(w00, w01, w1p, w1a, w1o, inp, ws);
  k_scan<<<1, 1024, 0, stream>>>((const int*)(ws + WS_BH), (int*)(ws + WS_CNT),
                                 (int*)(ws + WS_BASE), (int*)(ws + WS_OFF));
  k_scatter<<<NBLK, 256, 0, stream>>>((const int*)(ws + WS_PAIR),
                                      (const int*)(ws + WS_OFF),
                                      (int*)(ws + WS_ROWLIST));
  k_fwdA<<<256, 512, 0, stream>>>(inp, b00, b01, ws);
  k_fwdB<<<256, 512, 0, stream>>>(inp, b1p, b1a, b1o, ws, out);
}

// Round 11
// 60.636 us; speedup vs baseline: 2.0447x; 1.0075x over previous
//
#include <hip/hip_runtime.h>
#include <hip/hip_bf16.h>

#define BATCH 32768
#define NPAIR 64
#define NBLK  128

typedef __bf16 bf16x8 __attribute__((ext_vector_type(8)));
typedef float  f32x4  __attribute__((ext_vector_type(4)));
static_assert(sizeof(bf16x8) == 16, "bf16x8 must be 16B");

// ---- workspace byte offsets ----
#define WS_CNT      0
#define WS_BASE     256        /* padded (32-aligned) pair bases */
#define WS_BH       1024
#define WS_OFF      33792
#define WS_PAIR     66560
#define WS_ROWLIST  197632     /* padded, 34816 ints */
#define WS_WF00     336896     /* frag-major [m][NT16][KC2][64]x16B = 32KB/m */
#define WS_WF01     599040     /* [m][NT8][KC8][64] = 64KB/m */
#define WS_WF1P     1123328    /* 32KB/m */
#define WS_WF1A     1385472    /* [m][NT8][KC12][64] = 96KB/m */
#define WS_WF1O     2171904    /* [m][NT2][KC4][64] = 8KB/m */
#define WS_F2       2237440    /* [pos16<=2176][nb8][16][16] bf16 = 8.9MB */

__device__ __forceinline__ unsigned short f2bf(float x) {
  __bf16 h = (__bf16)x;
  return __builtin_bit_cast(unsigned short, h);
}

#define KEEP(x) asm volatile("" : "+v"(x))

__device__ __forceinline__ bf16x8 gather_frag(const float* __restrict__ inp,
                                              int rg, int colofs, int kc, int kcol) {
  bf16x8 a;
  if (rg >= 0) {
    const float* q = inp + (size_t)rg * 144 + colofs + kc * 32 + kcol;
    float4 u = *(const float4*)(q);
    float4 v = *(const float4*)(q + 4);
    a[0] = (__bf16)u.x; a[1] = (__bf16)u.y; a[2] = (__bf16)u.z; a[3] = (__bf16)u.w;
    a[4] = (__bf16)v.x; a[5] = (__bf16)v.y; a[6] = (__bf16)v.z; a[7] = (__bf16)v.w;
  } else {
    #pragma unroll
    for (int j = 0; j < 8; ++j) a[j] = (__bf16)0.f;
  }
  return a;
}

// Blocks 0..239: weight fp32 -> bf16 MFMA-fragment-major. Blocks 240..367: route.
__global__ __launch_bounds__(256) void k_combo(const float* __restrict__ w00,
                                               const float* __restrict__ w01,
                                               const float* __restrict__ w1p,
                                               const float* __restrict__ w1a,
                                               const float* __restrict__ w1o,
                                               const float* __restrict__ inp,
                                               char* __restrict__ ws) {
  __shared__ unsigned short lds[64 * 72];
  int bid = blockIdx.x;
  if (bid >= 240) {
    int* h = (int*)lds;
    int rbid = bid - 240;
    int t = threadIdx.x;
    if (t < NPAIR) h[t] = 0;
    __syncthreads();
    int r = rbid * 256 + t;
    const float* q = inp + (size_t)r * 144 + 128;
    float4 u0 = *(const float4*)(q + 0);
    float4 u1 = *(const float4*)(q + 4);
    float4 v0 = *(const float4*)(q + 8);
    float4 v1 = *(const float4*)(q + 12);
    int a0 = 0;
    if (u0.y > 0.5f) a0 = 1; if (u0.z > 0.5f) a0 = 2; if (u0.w > 0.5f) a0 = 3;
    if (u1.x > 0.5f) a0 = 4; if (u1.y > 0.5f) a0 = 5; if (u1.z > 0.5f) a0 = 6; if (u1.w > 0.5f) a0 = 7;
    int a1 = 0;
    if (v0.y > 0.5f) a1 = 1; if (v0.z > 0.5f) a1 = 2; if (v0.w > 0.5f) a1 = 3;
    if (v1.x > 0.5f) a1 = 4; if (v1.y > 0.5f) a1 = 5; if (v1.z > 0.5f) a1 = 6; if (v1.w > 0.5f) a1 = 7;
    int p = a0 * 8 + a1;
    ((int*)(ws + WS_PAIR))[r] = p;
    atomicAdd(&h[p], 1);
    __syncthreads();
    if (t < NPAIR) ((int*)(ws + WS_BH))[rbid * NPAIR + t] = h[t];
    return;
  }
  const float* src; char* dst; int I, O, lt, NT, KC;
  if (bid < 32)       { src = w00; dst = ws + WS_WF00; I = 64;  O = 256; lt = bid;       NT = 16; KC = 2; }
  else if (bid < 96)  { src = w01; dst = ws + WS_WF01; I = 256; O = 128; lt = bid - 32;  NT = 8;  KC = 8; }
  else if (bid < 128) { src = w1p; dst = ws + WS_WF1P; I = 64;  O = 256; lt = bid - 96;  NT = 16; KC = 2; }
  else if (bid < 224) { src = w1a; dst = ws + WS_WF1A; I = 384; O = 128; lt = bid - 128; NT = 8;  KC = 12; }
  else                { src = w1o; dst = ws + WS_WF1O; I = 128; O = 32;  lt = bid - 224; NT = 2;  KC = 4; }
  int tI = I >> 6;
  int tO = (O + 63) >> 6;
  int m   = lt / (tI * tO);
  int rem = lt % (tI * tO);
  int ib = rem / tO, ob = rem % tO;
  int tx = threadIdx.x & 63, ty = threadIdx.x >> 6;
  const float* s = src + (size_t)m * I * O;
  #pragma unroll 4
  for (int s4 = 0; s4 < 16; ++s4) {
    int li = s4 * 4 + ty;
    int o  = ob * 64 + tx;
    float v = (o < O) ? s[(size_t)(ib * 64 + li) * O + o] : 0.f;
    lds[li * 72 + tx] = f2bf(v);
  }
  __syncthreads();
  int lane = threadIdx.x & 63, u = threadIdx.x >> 6;
  int ln = lane & 15, lq = lane >> 4;
  #pragma unroll
  for (int it = 0; it < 2; ++it) {
    int fi  = it * 4 + u;
    int ntl = fi >> 1, kcl = fi & 1;
    int ntg = ob * 4 + ntl, kcg = ib * 2 + kcl;
    if (ntg * 16 < O) {
      bf16x8 f;
      #pragma unroll
      for (int j = 0; j < 8; ++j)
        f[j] = __builtin_bit_cast(__bf16, lds[(kcl * 32 + lq * 8 + j) * 72 + ntl * 16 + ln]);
      *(bf16x8*)(dst + (((size_t)(m * NT + ntg) * KC + kcg) * 64 + lane) * 16) = f;
    }
  }
}

// Scan: counts, PADDED (32-aligned) bases, per-(block,pair) scatter offsets.
__global__ __launch_bounds__(1024) void k_scan(const int* __restrict__ bh,
                                               int* __restrict__ cnt,
                                               int* __restrict__ base,
                                               int* __restrict__ off) {
  __shared__ int part[16][NPAIR];
  __shared__ int pb64[NPAIR];
  int tid = threadIdx.x;
  int p = tid & 63, c = tid >> 6;
  int loc[8]; int s = 0;
  #pragma unroll
  for (int i = 0; i < 8; ++i) { loc[i] = s; s += bh[(c * 8 + i) * NPAIR + p]; }
  part[c][p] = s;
  __syncthreads();
  if (tid < 64) {
    int run = 0;
    #pragma unroll
    for (int c2 = 0; c2 < 16; ++c2) { int v = part[c2][p]; part[c2][p] = run; run += v; }
    cnt[p] = run;
    int ntp = (run + 31) >> 5;
    int z = ntp;
    #pragma unroll
    for (int d = 1; d < 64; d <<= 1) { int y = __shfl_up(z, d); if (p >= d) z += y; }
    int pbase = (z - ntp) * 32;
    base[p] = pbase;
    pb64[p] = pbase;
  }
  __syncthreads();
  int add = part[c][p] + pb64[p];
  #pragma unroll
  for (int i = 0; i < 8; ++i) off[(c * 8 + i) * NPAIR + p] = loc[i] + add;
}

__global__ __launch_bounds__(256) void k_scatter(const int* __restrict__ pairArr,
                                                 const int* __restrict__ off,
                                                 int* __restrict__ rowlist) {
  __shared__ int h[NPAIR];
  int t = threadIdx.x;
  if (t < NPAIR) h[t] = 0;
  __syncthreads();
  int r = blockIdx.x * 256 + threadIdx.x;
  int p = pairArr[r];
  int rank = atomicAdd(&h[p], 1);
  rowlist[off[blockIdx.x * NPAIR + p] + rank] = r;
}

// Kernel A: e0-branch. LDS 80K exactly -> 2 blocks/CU (16 waves/CU).
// WF01 64K in LDS @0, H1 16K @65536; WF00 in registers (4 frags/lane).
// Grid 512 = 64 pairs x 8 slices.
__global__ __launch_bounds__(512, 4) void k_fwdA(
    const float* __restrict__ inp,
    const float* __restrict__ b00, const float* __restrict__ b01,
    char* __restrict__ ws)
{
  __shared__ char smem[81920];
  unsigned short* H1m = (unsigned short*)(smem + 65536);

  int p     = blockIdx.x >> 3;
  int slice = blockIdx.x & 7;
  int e0 = p >> 3;
  int cnt = ((const int*)(ws + WS_CNT))[p];
  int pbase = ((const int*)(ws + WS_BASE))[p];
  int ntp = (cnt + 31) >> 5;
  if (slice >= ntp) return;
  const int* rlbase = (const int*)(ws + WS_ROWLIST) + pbase;
  char* f2 = ws + WS_F2;

  int tid = threadIdx.x;
  // stage WF01[e0] (64KB) contiguously
  {
    const float4* s1 = (const float4*)(ws + WS_WF01 + (size_t)e0 * 65536);
    float4* d1 = (float4*)smem;
    #pragma unroll
    for (int i = 0; i < 8; ++i) d1[tid + i * 512] = s1[tid + i * 512];
  }

  int lane = tid & 63;
  int w    = tid >> 6;
  int ln = lane & 15, lq = lane >> 4, kcol = lq * 8;

  // WF00 in registers: wave w needs ntg = w*2+nt, kc 0..1 (lane-contiguous loads)
  bf16x8 w00f[2][2];
  #pragma unroll
  for (int nt = 0; nt < 2; ++nt)
    #pragma unroll
    for (int kc = 0; kc < 2; ++kc)
      w00f[nt][kc] = *(const bf16x8*)(ws + WS_WF00 + (size_t)e0 * 32768 +
                                      ((((w * 2 + nt) * 2 + kc) * 64 + lane) << 4));
  #pragma unroll
  for (int nt = 0; nt < 2; ++nt)
    #pragma unroll
    for (int kc = 0; kc < 2; ++kc) KEEP(w00f[nt][kc]);

  float bias00[2];
  #pragma unroll
  for (int nt = 0; nt < 2; ++nt) bias00[nt] = b00[e0 * 256 + w * 32 + nt * 16 + ln];
  float bias01 = b01[e0 * 128 + w * 16 + ln];

  const f32x4 z4 = {0.f, 0.f, 0.f, 0.f};
  __syncthreads();  // weights staged

  for (int t = slice; t < ntp; t += 8) {
    int nr = min(32, cnt - t * 32);
    int rb = pbase + t * 32;
    const int* rl = rlbase + t * 32;

    int rowA[2];
    #pragma unroll
    for (int mt = 0; mt < 2; ++mt) {
      int rloc = mt * 16 + ln;
      rowA[mt] = (rloc < nr) ? rl[rloc] : -1;
    }
    bf16x8 axf[2][2];
    #pragma unroll
    for (int mt = 0; mt < 2; ++mt)
      #pragma unroll
      for (int kc = 0; kc < 2; ++kc)
        axf[mt][kc] = gather_frag(inp, rowA[mt], 0, kc, kcol);

    // P1: L00 (reg weights) -> H1 (swizzled)
    #pragma unroll
    for (int nt = 0; nt < 2; ++nt) {
      int n = w * 32 + nt * 16 + ln;
      f32x4 acc[2] = {z4, z4};
      #pragma unroll
      for (int kc = 0; kc < 2; ++kc)
        #pragma unroll
        for (int mt = 0; mt < 2; ++mt)
          acc[mt] = __builtin_amdgcn_mfma_f32_16x16x32_bf16(axf[mt][kc], w00f[nt][kc], acc[mt], 0, 0, 0);
      #pragma unroll
      for (int mt = 0; mt < 2; ++mt)
        #pragma unroll
        for (int r = 0; r < 4; ++r) {
          int row = mt * 16 + lq * 4 + r;
          float v = fmaxf(acc[mt][r] + bias00[nt], 0.f);
          H1m[(row * 512 + ((n << 1) ^ ((row & 7) << 4))) >> 1] = f2bf(v);
        }
    }
    __syncthreads();  // H1 ready

    // P2: L01 (LDS weights) -> F2 global, 16x16-block layout
    {
      f32x4 acc[2] = {z4, z4};
      #pragma unroll
      for (int kc = 0; kc < 8; ++kc) {
        bf16x8 bfr = *(const bf16x8*)(smem + (((w * 8 + kc) * 64 + lane) << 4));
        #pragma unroll
        for (int mt = 0; mt < 2; ++mt) {
          int row = mt * 16 + ln;
          bf16x8 afr = *(const bf16x8*)&H1m[(row * 512 + (((kc * 32 + kcol) << 1) ^ ((row & 7) << 4))) >> 1];
          acc[mt] = __builtin_amdgcn_mfma_f32_16x16x32_bf16(afr, bfr, acc[mt], 0, 0, 0);
        }
      }
      #pragma unroll
      for (int mt = 0; mt < 2; ++mt) {
        int pos16 = (rb >> 4) + mt;
        char* bb = f2 + ((size_t)(pos16 * 8 + w) * 512);
        #pragma unroll
        for (int r = 0; r < 4; ++r) {
          float v = fmaxf(acc[mt][r] + bias01, 0.f);
          *(unsigned short*)(bb + (lq * 4 + r) * 32 + ln * 2) = f2bf(v);
        }
      }
    }
    __syncthreads();  // H1 reads done before next rewrite
  }
}

// Kernel B: e1-branch. LDS 72K -> 2 blocks/CU. WF1A kc<6 half (48K) @0,
// G 16K @49152, G2 8K @65536. WF1P / WF1A kc>=6 / WF1O in registers.
// 2 barriers per tile. Grid 512 = 64 pairs x 8 slices.
__global__ __launch_bounds__(512, 4) void k_fwdB(
    const float* __restrict__ inp,
    const float* __restrict__ b1p, const float* __restrict__ b1a,
    const float* __restrict__ b1o,
    char* __restrict__ ws, float* __restrict__ out)
{
  __shared__ char smem[73728];
  unsigned short* G  = (unsigned short*)(smem + 49152);
  unsigned short* G2 = (unsigned short*)(smem + 65536);

  int p     = blockIdx.x >> 3;
  int slice = blockIdx.x & 7;
  int e1 = p & 7;
  int cnt = ((const int*)(ws + WS_CNT))[p];
  int pbase = ((const int*)(ws + WS_BASE))[p];
  int ntp = (cnt + 31) >> 5;
  if (slice >= ntp) return;
  const int* rlbase = (const int*)(ws + WS_ROWLIST) + pbase;
  const char* f2 = ws + WS_F2;

  int tid = threadIdx.x;
  // stage WF1A[e1] kc 0..5 half (48KB): dst [w2][kc<6][64]x16B linear
  {
    const float4* s1 = (const float4*)(ws + WS_WF1A + (size_t)e1 * 98304);
    float4* d1 = (float4*)smem;
    #pragma unroll
    for (int i = 0; i < 6; ++i) {
      int fidx = tid + i * 512;          // 0..3071
      int chunk = fidx >> 6, within = fidx & 63;
      int w2 = chunk / 6, kc = chunk % 6;
      d1[fidx] = s1[(w2 * 12 + kc) * 64 + within];
    }
  }

  int lane = tid & 63;
  int w    = tid >> 6;
  int ln = lane & 15, lq = lane >> 4, kcol = lq * 8;

  // register weights (all lane-contiguous frag loads)
  bf16x8 w1pf[2][2];
  #pragma unroll
  for (int nt = 0; nt < 2; ++nt)
    #pragma unroll
    for (int kc = 0; kc < 2; ++kc)
      w1pf[nt][kc] = *(const bf16x8*)(ws + WS_WF1P + (size_t)e1 * 32768 +
                                      ((((w * 2 + nt) * 2 + kc) * 64 + lane) << 4));
  bf16x8 wa_hi[6];
  #pragma unroll
  for (int j = 0; j < 6; ++j)
    wa_hi[j] = *(const bf16x8*)(ws + WS_WF1A + (size_t)e1 * 98304 +
                                (((w * 12 + 6 + j) * 64 + lane) << 4));
  bf16x8 wo[4];
  if (w < 4) {
    #pragma unroll
    for (int kc = 0; kc < 4; ++kc)
      wo[kc] = *(const bf16x8*)(ws + WS_WF1O + (size_t)e1 * 8192 +
                                ((((w >> 1) * 4 + kc) * 64 + lane) << 4));
  }
  #pragma unroll
  for (int nt = 0; nt < 2; ++nt)
    #pragma unroll
    for (int kc = 0; kc < 2; ++kc) KEEP(w1pf[nt][kc]);
  #pragma unroll
  for (int j = 0; j < 6; ++j) KEEP(wa_hi[j]);
  if (w < 4) {
    #pragma unroll
    for (int kc = 0; kc < 4; ++kc) KEEP(wo[kc]);
  }

  float bias1p[2];
  #pragma unroll
  for (int nt = 0; nt < 2; ++nt) bias1p[nt] = b1p[e1 * 256 + w * 32 + nt * 16 + ln];
  float bias1a = b1a[e1 * 128 + w * 16 + ln];
  float bias1o = (w < 4) ? b1o[e1 * 32 + (w >> 1) * 16 + ln] : 0.f;

  const f32x4 z4 = {0.f, 0.f, 0.f, 0.f};
  __syncthreads();  // weights staged

  for (int t = slice; t < ntp; t += 8) {
    int nr = min(32, cnt - t * 32);
    int rb = pbase + t * 32;
    const int* rl = rlbase + t * 32;

    int rowA[2];
    #pragma unroll
    for (int mt = 0; mt < 2; ++mt) {
      int rloc = mt * 16 + ln;
      rowA[mt] = (rloc < nr) ? rl[rloc] : -1;
    }
    bf16x8 axf[2][2];
    #pragma unroll
    for (int mt = 0; mt < 2; ++mt)
      #pragma unroll
      for (int kc = 0; kc < 2; ++kc)
        axf[mt][kc] = gather_frag(inp, rowA[mt], 64, kc, kcol);

    // P1: L1p (reg weights) -> G (swizzled)
    #pragma unroll
    for (int nt = 0; nt < 2; ++nt) {
      int n = w * 32 + nt * 16 + ln;
      f32x4 acc[2] = {z4, z4};
      #pragma unroll
      for (int kc = 0; kc < 2; ++kc)
        #pragma unroll
        for (int mt = 0; mt < 2; ++mt)
          acc[mt] = __builtin_amdgcn_mfma_f32_16x16x32_bf16(axf[mt][kc], w1pf[nt][kc], acc[mt], 0, 0, 0);
      #pragma unroll
      for (int mt = 0; mt < 2; ++mt)
        #pragma unroll
        for (int r = 0; r < 4; ++r) {
          int row = mt * 16 + lq * 4 + r;
          float v = fmaxf(acc[mt][r] + bias1p[nt], 0.f);
          G[(row * 512 + ((n << 1) ^ ((row & 7) << 4))) >> 1] = f2bf(v);
        }
    }
    __syncthreads();  // bar1: G ready (also orders prev P3's G2 reads before this tile's G2 write)

    // P2: L1a = [F2-frags (kc<4) | G (kc>=4)] x [LDS (kc<6) | regs (kc>=6)] -> G2
    {
      f32x4 acc1a[2] = {z4, z4};
      #pragma unroll
      for (int kc = 0; kc < 12; ++kc) {
        bf16x8 bfr = (kc < 6)
          ? *(const bf16x8*)(smem + (((w * 6 + kc) * 64 + lane) << 4))
          : wa_hi[kc - 6];
        #pragma unroll
        for (int mt = 0; mt < 2; ++mt) {
          bf16x8 afr;
          if (kc < 4) {
            int pos16 = (rb >> 4) + mt;
            const char* bb = f2 + ((size_t)(pos16 * 8 + kc * 2 + (lq >> 1)) * 512);
            afr = *(const bf16x8*)(bb + ln * 32 + (lq & 1) * 16);
          } else {
            int kk = kc - 4;
            int row = mt * 16 + ln;
            afr = *(const bf16x8*)&G[(row * 512 + (((kk * 32 + kcol) << 1) ^ ((row & 7) << 4))) >> 1];
          }
          acc1a[mt] = __builtin_amdgcn_mfma_f32_16x16x32_bf16(afr, bfr, acc1a[mt], 0, 0, 0);
        }
      }
      int n = w * 16 + ln;
      #pragma unroll
      for (int mt = 0; mt < 2; ++mt)
        #pragma unroll
        for (int r = 0; r < 4; ++r) {
          int row = mt * 16 + lq * 4 + r;
          float v = fmaxf(acc1a[mt][r] + bias1a, 0.f);
          G2[(row * 256 + ((n << 1) ^ ((row & 7) << 4))) >> 1] = f2bf(v);
        }
    }
    __syncthreads();  // bar2: G2 ready; G reads done (next P1 may rewrite G)

    // P3 (waves 0..3): L1o: G2 @ wo -> out, fp32 scatter
    if (w < 4) {
      int mt = w & 1;
      int n  = (w >> 1) * 16 + ln;
      f32x4 acc = z4;
      #pragma unroll
      for (int kc = 0; kc < 4; ++kc) {
        int row = mt * 16 + ln;
        bf16x8 afr = *(const bf16x8*)&G2[(row * 256 + (((kc * 32 + kcol) << 1) ^ ((row & 7) << 4))) >> 1];
        acc = __builtin_amdgcn_mfma_f32_16x16x32_bf16(afr, wo[kc], acc, 0, 0, 0);
      }
      #pragma unroll
      for (int r = 0; r < 4; ++r) {
        int row = mt * 16 + lq * 4 + r;
        if (row < nr) {
          int rg = rl[row];
          out[(size_t)rg * 32 + n] = acc[r] + bias1o;
        }
      }
    }
  }
}

extern "C" void kernel_launch(void* const* d_in, const int* in_sizes, int n_in,
                              void* d_out, int out_size, void* d_ws, size_t ws_size,
                              hipStream_t stream) {
  const float* inp = (const float*)d_in[0];
  const float* w00 = (const float*)d_in[1];
  const float* b00 = (const float*)d_in[2];
  const float* w01 = (const float*)d_in[3];
  const float* b01 = (const float*)d_in[4];
  const float* w1p = (const float*)d_in[5];
  const float* b1p = (const float*)d_in[6];
  const float* w1a = (const float*)d_in[7];
  const float* b1a = (const float*)d_in[8];
  const float* w1o = (const float*)d_in[9];
  const float* b1o = (const float*)d_in[10];
  char*  ws  = (char*)d_ws;
  float* out = (float*)d_out;

  k_combo<<<368, 256, 0, stream>>>(w00, w01, w1p, w1a, w1o, inp, ws);
  k_scan<<<1, 1024, 0, stream>>>((const int*)(ws + WS_BH), (int*)(ws + WS_CNT),
                                 (int*)(ws + WS_BASE), (int*)(ws + WS_OFF));
  k_scatter<<<NBLK, 256, 0, stream>>>((const int*)(ws + WS_PAIR),
                                      (const int*)(ws + WS_OFF),
                                      (int*)(ws + WS_ROWLIST));
  k_fwdA<<<512, 512, 0, stream>>>(inp, b00, b01, ws);
  k_fwdB<<<512, 512, 0, stream>>>(inp, b1p, b1a, b1o, ws, out);
}